// Round 1
// baseline (400.970 us; speedup 1.0000x reference)
//
#include <hip/hip_runtime.h>
#include <hip/hip_bf16.h>

constexpr int NROW = 8192;
constexpr int INF  = 256;
constexpr int OUTF = 128;
constexpr int KSPLIT = 8;
constexpr int KCHUNK = NROW / KSPLIT; // 1024

typedef __bf16 bf16x8 __attribute__((ext_vector_type(8)));
typedef float  f32x4  __attribute__((ext_vector_type(4)));

// ---------------------------------------------------------------------------
// k1: h = x@W (f32 accum); f1 = h@a1, f2 = h@a2; ht = h^T in bf16 (for MFMA B)
// grid: NROW/32 blocks, 256 threads
// ---------------------------------------------------------------------------
__global__ __launch_bounds__(256) void k1(const float* __restrict__ x,
                                          const float* __restrict__ W,
                                          const float* __restrict__ a,
                                          __bf16* __restrict__ ht,
                                          float* __restrict__ f1,
                                          float* __restrict__ f2) {
  __shared__ float xs[32][INF];   // 32 KB
  __shared__ float hs[32][OUTF];  // 16 KB
  const int t  = threadIdx.x;
  const int i0 = blockIdx.x * 32;

  // stage x tile (32 rows x 256) coalesced as float4
  const f32x4* xsrc = reinterpret_cast<const f32x4*>(x + (size_t)i0 * INF);
  f32x4* xdst = reinterpret_cast<f32x4*>(&xs[0][0]);
  #pragma unroll
  for (int u = 0; u < (32 * INF / 4) / 256; ++u)
    xdst[u * 256 + t] = xsrc[u * 256 + t];
  __syncthreads();

  const int c  = t & 127;
  const int rg = t >> 7;  // 0/1 -> rows rg*16 .. rg*16+15
  float acc[16];
  #pragma unroll
  for (int r = 0; r < 16; ++r) acc[r] = 0.f;
  for (int k = 0; k < INF; ++k) {
    float wv = W[k * OUTF + c];
    #pragma unroll
    for (int r = 0; r < 16; ++r) acc[r] += xs[rg * 16 + r][k] * wv;
  }
  #pragma unroll
  for (int r = 0; r < 16; ++r) hs[rg * 16 + r][c] = acc[r];
  __syncthreads();

  // f1/f2 reductions: wave w handles rows w, w+4, ...
  const int wv = t >> 6, lane = t & 63;
  for (int r = wv; r < 32; r += 4) {
    float h0 = hs[r][lane * 2], h1 = hs[r][lane * 2 + 1];
    float s1 = h0 * a[lane * 2] + h1 * a[lane * 2 + 1];
    float s2 = h0 * a[OUTF + lane * 2] + h1 * a[OUTF + lane * 2 + 1];
    #pragma unroll
    for (int off = 32; off; off >>= 1) {
      s1 += __shfl_down(s1, off);
      s2 += __shfl_down(s2, off);
    }
    if (lane == 0) { f1[i0 + r] = s1; f2[i0 + r] = s2; }
  }

  // ht (transposed bf16 h): thread t -> col = t>>1, rows seg*16..+15
  const int col = t >> 1, seg = t & 1;
  bf16x8 v0, v1;
  #pragma unroll
  for (int r = 0; r < 8; ++r) v0[r] = (__bf16)hs[seg * 16 + r][col];
  #pragma unroll
  for (int r = 0; r < 8; ++r) v1[r] = (__bf16)hs[seg * 16 + 8 + r][col];
  __bf16* hdst = ht + (size_t)col * NROW + i0 + seg * 16;
  *reinterpret_cast<bf16x8*>(hdst)     = v0;
  *reinterpret_cast<bf16x8*>(hdst + 8) = v1;
}

// ---------------------------------------------------------------------------
// k2: per row i: bit-pack adj row, s[i] = sum_j adj * exp(lrelu(f1_i + f2_j))
// grid: NROW blocks, 256 threads
// ---------------------------------------------------------------------------
__global__ __launch_bounds__(256) void k2(const int* __restrict__ adj,
                                          const float* __restrict__ f1,
                                          const float* __restrict__ f2,
                                          unsigned long long* __restrict__ mask,
                                          float* __restrict__ s) {
  const int i = blockIdx.x;
  const int t = threadIdx.x;
  const int wv = t >> 6, lane = t & 63;
  const float f1i = f1[i];
  float acc = 0.f;
  for (int it = 0; it < NROW / 256; ++it) {
    int j = it * 256 + wv * 64 + lane;
    int av = adj[(size_t)i * NROW + j];
    float e = f1i + f2[j];
    e = e > 0.f ? e : 0.01f * e;
    float p = (av > 0) ? __expf(e) : 0.f;
    acc += p;
    unsigned long long m = __ballot(av > 0);
    if (lane == 0) mask[(size_t)i * (NROW / 64) + it * 4 + wv] = m;
  }
  #pragma unroll
  for (int off = 32; off; off >>= 1) acc += __shfl_down(acc, off);
  __shared__ float red[4];
  if (lane == 0) red[wv] = acc;
  __syncthreads();
  if (t == 0) s[i] = red[0] + red[1] + red[2] + red[3];
}

// ---------------------------------------------------------------------------
// k3: per block: 64 rows x K-chunk of 1024 j. Computes p = exp(lrelu) masked,
// writes att = p/s, and accumulates PV via bf16 MFMA 16x16x32 into out0.
// grid: (NROW/64)*KSPLIT blocks, 256 threads (4 waves; wave w -> rows w*16..)
// ---------------------------------------------------------------------------
__global__ __launch_bounds__(256) void k3(const __bf16* __restrict__ ht,
                                          const float* __restrict__ f1,
                                          const float* __restrict__ f2,
                                          const float* __restrict__ sum,
                                          const unsigned long long* __restrict__ mask,
                                          float* __restrict__ out0,
                                          float* __restrict__ att) {
  const int mb = blockIdx.x / KSPLIT;
  const int ks = blockIdx.x % KSPLIT;
  const int w    = threadIdx.x >> 6;
  const int lane = threadIdx.x & 63;
  const int lr = lane & 15;  // A-row / B-col / D-col lane component
  const int lc = lane >> 4;  // k-chunk (0..3)
  const int row0 = mb * 64 + w * 16;
  const int arow = row0 + lr;

  const float f1r    = f1[arow];
  const float inv_sA = 1.0f / sum[arow];

  f32x4 acc[8];
  #pragma unroll
  for (int n = 0; n < 8; ++n) acc[n] = (f32x4){0.f, 0.f, 0.f, 0.f};

  const int j0 = ks * KCHUNK;
  for (int k0 = j0; k0 < j0 + KCHUNK; k0 += 32) {
    unsigned long long mw = mask[(size_t)arow * (NROW / 64) + (k0 >> 6)];
    unsigned bits = (unsigned)(mw >> ((k0 & 32) + lc * 8)) & 0xFFu;

    f32x4 f2a = *reinterpret_cast<const f32x4*>(f2 + k0 + lc * 8);
    f32x4 f2b = *reinterpret_cast<const f32x4*>(f2 + k0 + lc * 8 + 4);

    f32x4 o0, o1;
    bf16x8 afrag;
    #pragma unroll
    for (int i2 = 0; i2 < 8; ++i2) {
      float e = f1r + (i2 < 4 ? f2a[i2] : f2b[i2 - 4]);
      e = e > 0.f ? e : 0.01f * e;
      float p = ((bits >> i2) & 1u) ? __expf(e) : 0.f;
      if (i2 < 4) o0[i2] = p * inv_sA; else o1[i2 - 4] = p * inv_sA;
      afrag[i2] = (__bf16)p;
    }
    // attention output row segment (f32)
    float* adst = att + (size_t)arow * NROW + k0 + lc * 8;
    *reinterpret_cast<f32x4*>(adst)     = o0;
    *reinterpret_cast<f32x4*>(adst + 4) = o1;

    // PV: 8 N-fragments of 16 cols each
    #pragma unroll
    for (int n = 0; n < 8; ++n) {
      bf16x8 b = *reinterpret_cast<const bf16x8*>(
          ht + (size_t)(n * 16 + lr) * NROW + k0 + lc * 8);
      acc[n] = __builtin_amdgcn_mfma_f32_16x16x32_bf16(afrag, b, acc[n], 0, 0, 0);
    }
  }

  // epilogue: D row = row0 + lc*4 + i, col = n*16 + lr ; scale by 1/s, atomic
  float inv_sD[4];
  #pragma unroll
  for (int i2 = 0; i2 < 4; ++i2) inv_sD[i2] = 1.0f / sum[row0 + lc * 4 + i2];
  #pragma unroll
  for (int n = 0; n < 8; ++n) {
    #pragma unroll
    for (int i2 = 0; i2 < 4; ++i2) {
      atomicAdd(&out0[(size_t)(row0 + lc * 4 + i2) * OUTF + n * 16 + lr],
                acc[n][i2] * inv_sD[i2]);
    }
  }
}

// ---------------------------------------------------------------------------
extern "C" void kernel_launch(void* const* d_in, const int* in_sizes, int n_in,
                              void* d_out, int out_size, void* d_ws, size_t ws_size,
                              hipStream_t stream) {
  const float* x   = (const float*)d_in[0];
  const int*   adj = (const int*)d_in[1];
  const float* W   = (const float*)d_in[2];
  const float* a   = (const float*)d_in[3];

  float* out0 = (float*)d_out;                       // 8192 x 128
  float* att  = (float*)d_out + (size_t)NROW * OUTF; // 8192 x 8192

  char* ws = (char*)d_ws;
  __bf16* ht = (__bf16*)ws;                                        // 2 MB
  unsigned long long* mask = (unsigned long long*)(ws + (2 << 20)); // 8 MB
  float* f1 = (float*)(ws + (10 << 20));
  float* f2 = (float*)(ws + (10 << 20) + 32 * 1024);
  float* s  = (float*)(ws + (10 << 20) + 64 * 1024);

  hipMemsetAsync(out0, 0, (size_t)NROW * OUTF * sizeof(float), stream);
  k1<<<NROW / 32, 256, 0, stream>>>(x, W, a, ht, f1, f2);
  k2<<<NROW, 256, 0, stream>>>(adj, f1, f2, mask, s);
  k3<<<(NROW / 64) * KSPLIT, 256, 0, stream>>>(ht, f1, f2, s, mask, out0, att);
}

// Round 2
// 245.818 us; speedup vs baseline: 1.6312x; 1.6312x over previous
//
#include <hip/hip_runtime.h>
#include <hip/hip_bf16.h>

constexpr int NROW = 8192;
constexpr int INF  = 256;
constexpr int OUTF = 128;
constexpr int KSPLIT = 8;
constexpr int KCHUNK = NROW / KSPLIT; // 1024

typedef __bf16 bf16x8 __attribute__((ext_vector_type(8)));
typedef float  f32x4  __attribute__((ext_vector_type(4)));
typedef int    i32x4  __attribute__((ext_vector_type(4)));
typedef unsigned long long u64;

// ---------------------------------------------------------------------------
// k1: h = x@W (f32 accum); f1 = h@a1, f2 = h@a2; ht = h^T in bf16 (for MFMA B)
// grid: NROW/32 blocks, 256 threads
// ---------------------------------------------------------------------------
__global__ __launch_bounds__(256) void k1(const float* __restrict__ x,
                                          const float* __restrict__ W,
                                          const float* __restrict__ a,
                                          __bf16* __restrict__ ht,
                                          float* __restrict__ f1,
                                          float* __restrict__ f2) {
  __shared__ float xs[32][INF];   // 32 KB
  __shared__ float hs[32][OUTF];  // 16 KB
  const int t  = threadIdx.x;
  const int i0 = blockIdx.x * 32;

  const f32x4* xsrc = reinterpret_cast<const f32x4*>(x + (size_t)i0 * INF);
  f32x4* xdst = reinterpret_cast<f32x4*>(&xs[0][0]);
  #pragma unroll
  for (int u = 0; u < (32 * INF / 4) / 256; ++u)
    xdst[u * 256 + t] = xsrc[u * 256 + t];
  __syncthreads();

  const int c  = t & 127;
  const int rg = t >> 7;  // 0/1 -> rows rg*16 .. rg*16+15
  float acc[16];
  #pragma unroll
  for (int r = 0; r < 16; ++r) acc[r] = 0.f;
  for (int k = 0; k < INF; ++k) {
    float wv = W[k * OUTF + c];
    #pragma unroll
    for (int r = 0; r < 16; ++r) acc[r] += xs[rg * 16 + r][k] * wv;
  }
  #pragma unroll
  for (int r = 0; r < 16; ++r) hs[rg * 16 + r][c] = acc[r];
  __syncthreads();

  const int wv = t >> 6, lane = t & 63;
  for (int r = wv; r < 32; r += 4) {
    float h0 = hs[r][lane * 2], h1 = hs[r][lane * 2 + 1];
    float s1 = h0 * a[lane * 2] + h1 * a[lane * 2 + 1];
    float s2 = h0 * a[OUTF + lane * 2] + h1 * a[OUTF + lane * 2 + 1];
    #pragma unroll
    for (int off = 32; off; off >>= 1) {
      s1 += __shfl_down(s1, off);
      s2 += __shfl_down(s2, off);
    }
    if (lane == 0) { f1[i0 + r] = s1; f2[i0 + r] = s2; }
  }

  const int col = t >> 1, seg = t & 1;
  bf16x8 v0, v1;
  #pragma unroll
  for (int r = 0; r < 8; ++r) v0[r] = (__bf16)hs[seg * 16 + r][col];
  #pragma unroll
  for (int r = 0; r < 8; ++r) v1[r] = (__bf16)hs[seg * 16 + 8 + r][col];
  __bf16* hdst = ht + (size_t)col * NROW + i0 + seg * 16;
  *reinterpret_cast<bf16x8*>(hdst)     = v0;
  *reinterpret_cast<bf16x8*>(hdst + 8) = v1;
}

// ---------------------------------------------------------------------------
// k2: one wave per row. int4 vectorized adj loads (nontemporal), nibble-pack
// mask via __shfl_xor OR-reduce, row sum of masked exp.
// grid: NROW/4 blocks, 256 threads (4 waves, wave w -> row blockIdx*4+w)
// ---------------------------------------------------------------------------
__global__ __launch_bounds__(256) void k2(const int* __restrict__ adj,
                                          const float* __restrict__ f1,
                                          const float* __restrict__ f2,
                                          u64* __restrict__ mask,
                                          float* __restrict__ s) {
  const int row  = blockIdx.x * 4 + (threadIdx.x >> 6);
  const int lane = threadIdx.x & 63;
  const float f1i = f1[row];
  const i32x4* arow = reinterpret_cast<const i32x4*>(adj + (size_t)row * NROW);
  const f32x4* f2v  = reinterpret_cast<const f32x4*>(f2);

  float acc = 0.f;
  for (int it = 0; it < NROW / 256; ++it) {  // 256 j per iter (lane*4)
    i32x4 av = __builtin_nontemporal_load(arow + it * 64 + lane);
    f32x4 fv = f2v[it * 64 + lane];
    unsigned nib = (av[0] > 0) | ((av[1] > 0) << 1) | ((av[2] > 0) << 2) |
                   ((av[3] > 0) << 3);
    #pragma unroll
    for (int b = 0; b < 4; ++b) {
      float e = f1i + fv[b];
      e = e > 0.f ? e : 0.01f * e;
      acc += ((nib >> b) & 1u) ? __expf(e) : 0.f;
    }
    u64 m = (u64)nib << (4 * (lane & 15));
    m |= __shfl_xor(m, 1);
    m |= __shfl_xor(m, 2);
    m |= __shfl_xor(m, 4);
    m |= __shfl_xor(m, 8);
    if ((lane & 15) == 0)
      mask[(size_t)row * (NROW / 64) + it * 4 + (lane >> 4)] = m;
  }
  #pragma unroll
  for (int off = 32; off; off >>= 1) acc += __shfl_down(acc, off);
  if (lane == 0) s[row] = acc;
}

// ---------------------------------------------------------------------------
// k3: 64 rows x 1024-j chunk per block. p = exp(lrelu) masked; att = p/s
// (nontemporal stores); PV via bf16 MFMA 16x16x32 accumulated, atomicAdd out0.
// k unrolled x2 (64 j / iter). f2 chunk staged in LDS.
// grid: (NROW/64)*KSPLIT blocks, 256 threads
// ---------------------------------------------------------------------------
__global__ __launch_bounds__(256) void k3(const __bf16* __restrict__ ht,
                                          const float* __restrict__ f1,
                                          const float* __restrict__ f2,
                                          const float* __restrict__ sum,
                                          const u64* __restrict__ mask,
                                          float* __restrict__ out0,
                                          float* __restrict__ att) {
  __shared__ float f2s[KCHUNK];  // 4 KB
  const int mb = blockIdx.x / KSPLIT;
  const int ks = blockIdx.x % KSPLIT;
  const int t    = threadIdx.x;
  const int w    = t >> 6;
  const int lane = t & 63;
  const int lr = lane & 15;
  const int lc = lane >> 4;
  const int row0 = mb * 64 + w * 16;
  const int arow = row0 + lr;
  const int j0 = ks * KCHUNK;

  // stage f2 chunk
  {
    const f32x4* src = reinterpret_cast<const f32x4*>(f2 + j0);
    f32x4* dst = reinterpret_cast<f32x4*>(f2s);
    if (t < KCHUNK / 4) dst[t] = src[t];
  }
  __syncthreads();

  const float f1r    = f1[arow];
  const float inv_sA = 1.0f / sum[arow];
  const u64* mrow = mask + (size_t)arow * (NROW / 64) + (j0 >> 6);

  f32x4 acc[8];
  #pragma unroll
  for (int n = 0; n < 8; ++n) acc[n] = (f32x4){0.f, 0.f, 0.f, 0.f};

  for (int kk = 0; kk < KCHUNK; kk += 64) {
    const u64 mw = mrow[kk >> 6];
    bf16x8 afrag[2];
    #pragma unroll
    for (int h = 0; h < 2; ++h) {
      const unsigned bits = (unsigned)(mw >> (h * 32 + lc * 8)) & 0xFFu;
      const int base = kk + h * 32 + lc * 8;
      f32x4 o0, o1;
      #pragma unroll
      for (int i2 = 0; i2 < 8; ++i2) {
        float e = f1r + f2s[base + i2];
        e = e > 0.f ? e : 0.01f * e;
        float p = ((bits >> i2) & 1u) ? __expf(e) : 0.f;
        if (i2 < 4) o0[i2] = p * inv_sA; else o1[i2 - 4] = p * inv_sA;
        afrag[h][i2] = (__bf16)p;
      }
      float* adst = att + (size_t)arow * NROW + j0 + base;
      __builtin_nontemporal_store(o0, reinterpret_cast<f32x4*>(adst));
      __builtin_nontemporal_store(o1, reinterpret_cast<f32x4*>(adst + 4));
    }
    // PV: 8 N-fragments x 2 k-steps
    #pragma unroll
    for (int n = 0; n < 8; ++n) {
      const __bf16* hb = ht + (size_t)(n * 16 + lr) * NROW + j0 + kk + lc * 8;
      bf16x8 b0 = *reinterpret_cast<const bf16x8*>(hb);
      bf16x8 b1 = *reinterpret_cast<const bf16x8*>(hb + 32);
      acc[n] = __builtin_amdgcn_mfma_f32_16x16x32_bf16(afrag[0], b0, acc[n], 0, 0, 0);
      acc[n] = __builtin_amdgcn_mfma_f32_16x16x32_bf16(afrag[1], b1, acc[n], 0, 0, 0);
    }
  }

  float inv_sD[4];
  #pragma unroll
  for (int i2 = 0; i2 < 4; ++i2) inv_sD[i2] = 1.0f / sum[row0 + lc * 4 + i2];
  #pragma unroll
  for (int n = 0; n < 8; ++n) {
    #pragma unroll
    for (int i2 = 0; i2 < 4; ++i2) {
      atomicAdd(&out0[(size_t)(row0 + lc * 4 + i2) * OUTF + n * 16 + lr],
                acc[n][i2] * inv_sD[i2]);
    }
  }
}

// ---------------------------------------------------------------------------
extern "C" void kernel_launch(void* const* d_in, const int* in_sizes, int n_in,
                              void* d_out, int out_size, void* d_ws, size_t ws_size,
                              hipStream_t stream) {
  const float* x   = (const float*)d_in[0];
  const int*   adj = (const int*)d_in[1];
  const float* W   = (const float*)d_in[2];
  const float* a   = (const float*)d_in[3];

  float* out0 = (float*)d_out;                       // 8192 x 128
  float* att  = (float*)d_out + (size_t)NROW * OUTF; // 8192 x 8192

  char* ws = (char*)d_ws;
  __bf16* ht = (__bf16*)ws;                                         // 2 MB
  u64* mask = (u64*)(ws + (2 << 20));                               // 8 MB
  float* f1 = (float*)(ws + (10 << 20));
  float* f2 = (float*)(ws + (10 << 20) + 32 * 1024);
  float* s  = (float*)(ws + (10 << 20) + 64 * 1024);

  hipMemsetAsync(out0, 0, (size_t)NROW * OUTF * sizeof(float), stream);
  k1<<<NROW / 32, 256, 0, stream>>>(x, W, a, ht, f1, f2);
  k2<<<NROW / 4, 256, 0, stream>>>(adj, f1, f2, mask, s);
  k3<<<(NROW / 64) * KSPLIT, 256, 0, stream>>>(ht, f1, f2, s, mask, out0, att);
}